// Round 8
// baseline (303.137 us; speedup 1.0000x reference)
//
#include <hip/hip_runtime.h>

#define N_NODES 100000
#define N_EDGES 1000000
#define D 64
#define NB1 ((N_NODES + 1023) / 1024)   // 98 scan chunks of 1024
#define UAG 8                            // agg2 unroll: 2*UAG=16 edges per iter

// Zero the degree array + the 16-entry pairs pad (safe overread target for agg2).
__global__ __launch_bounds__(256) void gine_zero(int4* __restrict__ deg4, int n4,
                                                 int4* __restrict__ pad) {
    int i = blockIdx.x * 256 + threadIdx.x;
    if (i < n4) deg4[i] = make_int4(0, 0, 0, 0);
    if (blockIdx.x == 0 && threadIdx.x < 8) pad[threadIdx.x] = make_int4(0, 0, 0, 0);
}

// Convert x (fp32) -> xh (bf16 RNE, packed pairs: word i = feat 2i | feat 2i+1 <<16).
__device__ __forceinline__ unsigned int bf16_rne(float f) {
    unsigned int b = __float_as_uint(f);
    return (b + 0x7FFFu + ((b >> 16) & 1u)) >> 16;
}
__global__ __launch_bounds__(256) void gine_x2h(const float* __restrict__ x,
                                                unsigned int* __restrict__ xh2) {
    int i = blockIdx.x * 256 + threadIdx.x;
    if (i < N_NODES * D / 8) {
        float4 q0 = ((const float4*)x)[i * 2 + 0];
        float4 q1 = ((const float4*)x)[i * 2 + 1];
        uint4 o;
        o.x = bf16_rne(q0.x) | (bf16_rne(q0.y) << 16);
        o.y = bf16_rne(q0.z) | (bf16_rne(q0.w) << 16);
        o.z = bf16_rne(q1.x) | (bf16_rne(q1.y) << 16);
        o.w = bf16_rne(q1.z) | (bf16_rne(q1.w) << 16);
        ((uint4*)xh2)[i] = o;
    }
}

// ============ CSR-by-dst build ============

__global__ __launch_bounds__(256) void gine_hist(const int* __restrict__ ei,
                                                 int* __restrict__ deg) {
    int e = (blockIdx.x * 256 + threadIdx.x) * 4;
    if (e + 3 < N_EDGES) {
        int4 t = *(const int4*)(ei + N_EDGES + e);
        atomicAdd(&deg[t.x], 1); atomicAdd(&deg[t.y], 1);
        atomicAdd(&deg[t.z], 1); atomicAdd(&deg[t.w], 1);
    } else {
        for (int j = e; j < N_EDGES; ++j) atomicAdd(&deg[ei[N_EDGES + j]], 1);
    }
}

__global__ __launch_bounds__(256) void gine_scan1(const int* __restrict__ deg,
                                                  int* __restrict__ excl,
                                                  int* __restrict__ bs) {
    __shared__ int wt[4];
    int tid = threadIdx.x, lane = tid & 63, wid = tid >> 6;
    int i0 = blockIdx.x * 1024 + tid * 4;
    int v0 = 0, v1 = 0, v2 = 0, v3 = 0;
    if (i0 + 3 < N_NODES) {
        int4 q = *(const int4*)(deg + i0);
        v0 = q.x; v1 = q.y; v2 = q.z; v3 = q.w;
    } else if (i0 < N_NODES) {
        v0 = deg[i0];
        if (i0 + 1 < N_NODES) v1 = deg[i0 + 1];
        if (i0 + 2 < N_NODES) v2 = deg[i0 + 2];
    }
    int tsum = v0 + v1 + v2 + v3;
    int s = tsum;
    #pragma unroll
    for (int off = 1; off < 64; off <<= 1) {
        int t = __shfl_up(s, off, 64);
        if (lane >= off) s += t;
    }
    if (lane == 63) wt[wid] = s;
    __syncthreads();
    int woff = 0;
    #pragma unroll
    for (int w = 0; w < 4; ++w) if (w < wid) woff += wt[w];
    int e0 = woff + s - tsum;
    if (i0 + 3 < N_NODES) {
        int4 q; q.x = e0; q.y = e0 + v0; q.z = e0 + v0 + v1; q.w = e0 + v0 + v1 + v2;
        *(int4*)(excl + i0) = q;
    } else if (i0 < N_NODES) {
        excl[i0] = e0;
        if (i0 + 1 < N_NODES) excl[i0 + 1] = e0 + v0;
        if (i0 + 2 < N_NODES) excl[i0 + 2] = e0 + v0 + v1;
    }
    if (tid == 255) bs[blockIdx.x] = woff + s;
}

__global__ __launch_bounds__(128) void gine_scan2(int* __restrict__ bs) {
    __shared__ int wt[2];
    int tid = threadIdx.x, lane = tid & 63, wid = tid >> 6;
    int v = (tid < NB1) ? bs[tid] : 0;
    int s = v;
    #pragma unroll
    for (int off = 1; off < 64; off <<= 1) {
        int t = __shfl_up(s, off, 64);
        if (lane >= off) s += t;
    }
    if (lane == 63) wt[wid] = s;
    __syncthreads();
    int woff = (wid == 1) ? wt[0] : 0;
    if (tid < NB1) bs[tid] = woff + s - v;
}

__global__ __launch_bounds__(256) void gine_scan3(const int* __restrict__ bs,
                                                  int* __restrict__ row_start,
                                                  int* __restrict__ counter) {
    int i = blockIdx.x * 256 + threadIdx.x;
    if (i < N_NODES) {
        int rs = row_start[i] + bs[i >> 10];
        row_start[i] = rs;
        counter[i] = rs;
    }
    if (blockIdx.x == 0 && threadIdx.x == 0) row_start[N_NODES] = N_EDGES;
}

// Scatter packed BYTE OFFSETS (ea_off = e*256 fp32, xh_off = src*128 bf16), dst-sorted.
__global__ __launch_bounds__(256) void gine_fill(const int* __restrict__ ei,
                                                 int* __restrict__ counter,
                                                 int2* __restrict__ pairs) {
    int e = (blockIdx.x * 256 + threadIdx.x) * 4;
    if (e + 3 < N_EDGES) {
        int4 sv = *(const int4*)(ei + e);
        int4 tv = *(const int4*)(ei + N_EDGES + e);
        int p;
        p = atomicAdd(&counter[tv.x], 1); pairs[p] = make_int2((e + 0) << 8, sv.x << 7);
        p = atomicAdd(&counter[tv.y], 1); pairs[p] = make_int2((e + 1) << 8, sv.y << 7);
        p = atomicAdd(&counter[tv.z], 1); pairs[p] = make_int2((e + 2) << 8, sv.z << 7);
        p = atomicAdd(&counter[tv.w], 1); pairs[p] = make_int2((e + 3) << 8, sv.w << 7);
    } else {
        for (int j = e; j < N_EDGES; ++j) {
            int t = ei[N_EDGES + j];
            int p = atomicAdd(&counter[t], 1);
            pairs[p] = make_int2(j << 8, ei[j] << 7);
        }
    }
}

// Kernel A: gather-aggregate. Wave = 1 node; lanes = 2 halves x 32.
// Each half processes a different edge; lane covers feature pair (2s,2s+1).
// Per 16 edges: 8 dwordx2 (ea) + 8 dword (xh) vector loads — half of before.
__global__ __launch_bounds__(256) void gine_agg2(const unsigned short* __restrict__ xh,
                                                 const float* __restrict__ ea,
                                                 const int* __restrict__ row_start,
                                                 const int2* __restrict__ pairs,
                                                 float* __restrict__ out) {
    int lane = threadIdx.x & 63;
    int wid = __builtin_amdgcn_readfirstlane(threadIdx.x >> 6);
    int half = lane >> 5;            // which edge of the pair
    int s2 = lane & 31;              // feature-pair index
    int node = blockIdx.x * 4 + wid; // wave-uniform; grid exact (25000*4)
    int beg = row_start[node], end = row_start[node + 1];
    float ax = 0.0f, ay = 0.0f;
    for (int k = beg; k < end; k += 2 * UAG) {
        const int2* pk = pairs + k;  // uniform; 16-entry zero pad makes pk[0..15] safe
        #pragma unroll
        for (int j = 0; j < UAG; ++j) {
            int2 pa = pk[2 * j];     // uniform -> wide s_load
            int2 pb = pk[2 * j + 1];
            int eoff = half ? pb.x : pa.x;   // per-half select (cndmask)
            int xoff = half ? pb.y : pa.y;
            float2 ev = *((const float2*)((const char*)ea + eoff) + s2);
            unsigned int xv = *((const unsigned int*)((const char*)xh + xoff) + s2);
            float xlo = __uint_as_float(xv << 16);
            float xhi = __uint_as_float(xv & 0xFFFF0000u);
            float mx = fmaxf(ev.x + xlo, 0.0f);
            float my = fmaxf(ev.y + xhi, 0.0f);
            bool ok = (k + 2 * j + half) < end;
            ax += ok ? mx : 0.0f;
            ay += ok ? my : 0.0f;
        }
    }
    ax += __shfl_xor(ax, 32, 64);    // combine the two halves
    ay += __shfl_xor(ay, 32, 64);
    if (half == 0) {
        ((float2*)(out + node * D))[s2] = make_float2(ax, ay);
    }
}

// Kernel B: in-place out = relu((out + (1+eps)x) @ W^T + b).
__global__ __launch_bounds__(256) void gine_lin(float* __restrict__ out,
                                                const float* __restrict__ x,
                                                const float* __restrict__ W,
                                                const float* __restrict__ bias,
                                                const float* __restrict__ eps) {
    __shared__ float Wl[D][D + 1];             // Wl[dd][o] = W[o][dd]
    __shared__ __align__(16) float hl[4][4][D];
    int tid = threadIdx.x;
    for (int i = tid; i < D * D; i += 256) {
        int o = i >> 6, dd = i & 63;
        Wl[dd][o] = W[i];
    }
    __syncthreads();

    int o = tid & 63;
    int wid = __builtin_amdgcn_readfirstlane(threadIdx.x >> 6);
    float bv = bias[o];
    float s = 1.0f + eps[0];
    int base = blockIdx.x * 64 + wid * 16;

    for (int t = 0; t < 4; ++t) {
        int r0 = base + t * 4;
        #pragma unroll
        for (int r = 0; r < 4; ++r) {
            int rr = r0 + r;
            float hv = 0.0f;
            if (rr < N_NODES) hv = out[rr * D + o] + s * x[rr * D + o];
            hl[wid][r][o] = hv;                // wave-private: no barrier needed
        }
        float a0 = bv, a1 = bv, a2 = bv, a3 = bv;
        #pragma unroll
        for (int dq = 0; dq < 16; ++dq) {
            float4 h0 = *(const float4*)&hl[wid][0][dq * 4];
            float4 h1 = *(const float4*)&hl[wid][1][dq * 4];
            float4 h2 = *(const float4*)&hl[wid][2][dq * 4];
            float4 h3 = *(const float4*)&hl[wid][3][dq * 4];
            float w0 = Wl[dq * 4 + 0][o];
            float w1 = Wl[dq * 4 + 1][o];
            float w2 = Wl[dq * 4 + 2][o];
            float w3 = Wl[dq * 4 + 3][o];
            a0 = fmaf(h0.w, w3, fmaf(h0.z, w2, fmaf(h0.y, w1, fmaf(h0.x, w0, a0))));
            a1 = fmaf(h1.w, w3, fmaf(h1.z, w2, fmaf(h1.y, w1, fmaf(h1.x, w0, a1))));
            a2 = fmaf(h2.w, w3, fmaf(h2.z, w2, fmaf(h2.y, w1, fmaf(h2.x, w0, a2))));
            a3 = fmaf(h3.w, w3, fmaf(h3.z, w2, fmaf(h3.y, w1, fmaf(h3.x, w0, a3))));
        }
        if (r0 + 0 < N_NODES) out[(r0 + 0) * D + o] = fmaxf(a0, 0.0f);
        if (r0 + 1 < N_NODES) out[(r0 + 1) * D + o] = fmaxf(a1, 0.0f);
        if (r0 + 2 < N_NODES) out[(r0 + 2) * D + o] = fmaxf(a2, 0.0f);
        if (r0 + 3 < N_NODES) out[(r0 + 3) * D + o] = fmaxf(a3, 0.0f);
    }
}

// ============ fallback path (atomic scatter) ============

__global__ __launch_bounds__(256) void gine_init(const float* __restrict__ x,
                                                 const float* __restrict__ eps,
                                                 float* __restrict__ out, int n4) {
    int i = blockIdx.x * blockDim.x + threadIdx.x;
    float s = 1.0f + eps[0];
    if (i < n4) {
        float4 v = ((const float4*)x)[i];
        v.x *= s; v.y *= s; v.z *= s; v.w *= s;
        ((float4*)out)[i] = v;
    }
}

__global__ __launch_bounds__(256) void gine_edges(const float* __restrict__ x,
                                                  const int* __restrict__ ei,
                                                  const float* __restrict__ ea,
                                                  float* __restrict__ out) {
    int e = blockIdx.x * (blockDim.x >> 6) + (threadIdx.x >> 6);
    int d = threadIdx.x & 63;
    if (e < N_EDGES) {
        int s = ei[e];
        int t = ei[N_EDGES + e];
        float m = x[(long long)s * D + d] + ea[(long long)e * D + d];
        m = fmaxf(m, 0.0f);
        atomicAdd(&out[(long long)t * D + d], m);
    }
}

__global__ __launch_bounds__(256) void gine_linear(float* __restrict__ h,
                                                   const float* __restrict__ W,
                                                   const float* __restrict__ b) {
    __shared__ float Wl[D][D + 1];
    __shared__ float bl[D];
    int tid = threadIdx.x;
    for (int i = tid; i < D * D; i += 256) Wl[i >> 6][i & 63] = W[i];
    if (tid < D) bl[tid] = b[tid];
    __syncthreads();
    int o = tid & 63;
    int row = blockIdx.x * 4 + (tid >> 6);
    if (row < N_NODES) {
        const float* hr = h + (long long)row * D;
        float acc = bl[o];
        #pragma unroll
        for (int d = 0; d < D; ++d) acc = fmaf(hr[d], Wl[o][d], acc);
        h[(long long)row * D + o] = fmaxf(acc, 0.0f);
    }
}

extern "C" void kernel_launch(void* const* d_in, const int* in_sizes, int n_in,
                              void* d_out, int out_size, void* d_ws, size_t ws_size,
                              hipStream_t stream) {
    const float* x   = (const float*)d_in[0];
    const int*   ei  = (const int*)d_in[1];   // int32 on device (harness narrows int64)
    const float* ea  = (const float*)d_in[2];
    const float* W   = (const float*)d_in[3];
    const float* b   = (const float*)d_in[4];
    const float* eps = (const float*)d_in[5];
    float* out = (float*)d_out;

    // ws layout: pairs[E+16] int2 | xh[N*D] bf16 | deg[N] | row_start[N+1] | counter[N] | bs[128]
    size_t need = ((size_t)N_EDGES + 16) * 8 + (size_t)N_NODES * D * 2 +
                  ((size_t)N_NODES * 3 + 1 + 128) * sizeof(int);
    if (ws_size >= need) {
        int2* pairs          = (int2*)d_ws;
        unsigned short* xh   = (unsigned short*)(pairs + N_EDGES + 16);
        int* deg             = (int*)(xh + (size_t)N_NODES * D);
        int* row_start       = deg + N_NODES;
        int* counter         = row_start + N_NODES + 1;
        int* bs              = counter + N_NODES;

        gine_x2h<<<(N_NODES * D / 8 + 255) / 256, 256, 0, stream>>>(x, (unsigned int*)xh);
        gine_zero<<<(N_NODES / 4 + 255) / 256, 256, 0, stream>>>(
            (int4*)deg, N_NODES / 4, (int4*)(pairs + N_EDGES));
        int ebl = (N_EDGES / 4 + 255) / 256;  // 977
        gine_hist<<<ebl, 256, 0, stream>>>(ei, deg);
        gine_scan1<<<NB1, 256, 0, stream>>>(deg, row_start, bs);
        gine_scan2<<<1, 128, 0, stream>>>(bs);
        gine_scan3<<<(N_NODES + 255) / 256, 256, 0, stream>>>(bs, row_start, counter);
        gine_fill<<<ebl, 256, 0, stream>>>(ei, counter, pairs);
        gine_agg2<<<N_NODES / 4, 256, 0, stream>>>(xh, ea, row_start, pairs, out);
        gine_lin<<<(N_NODES + 63) / 64, 256, 0, stream>>>(out, x, W, b, eps);
    } else {
        int n4 = (N_NODES * D) / 4;
        gine_init<<<(n4 + 255) / 256, 256, 0, stream>>>(x, eps, out, n4);
        gine_edges<<<(N_EDGES + 3) / 4, 256, 0, stream>>>(x, ei, ea, out);
        gine_linear<<<(N_NODES + 3) / 4, 256, 0, stream>>>(out, W, b);
    }
}

// Round 9
// 221.313 us; speedup vs baseline: 1.3697x; 1.3697x over previous
//
#include <hip/hip_runtime.h>

#define N_NODES 100000
#define N_EDGES 1000000
#define D 64

typedef float f2v __attribute__((ext_vector_type(2)));

__device__ __forceinline__ unsigned int bf16_rne(float f) {
    unsigned int b = __float_as_uint(f);
    return (b + 0x7FFFu + ((b >> 16) & 1u)) >> 16;
}
__device__ __forceinline__ float bf16_lo(unsigned int v) { return __uint_as_float(v << 16); }
__device__ __forceinline__ float bf16_hi(unsigned int v) { return __uint_as_float(v & 0xFFFF0000u); }
__device__ __forceinline__ float bf16_f(unsigned short u) {
    return __uint_as_float(((unsigned int)u) << 16);
}

// prep: xh = bf16(x) (packed pairs), ob = 0. 8 elems/thread.
__global__ __launch_bounds__(256) void gine_prep(const float* __restrict__ x,
                                                 uint4* __restrict__ xh4,
                                                 uint4* __restrict__ ob4) {
    int i = blockIdx.x * 256 + threadIdx.x;
    if (i < N_NODES * D / 8) {
        float4 q0 = ((const float4*)x)[i * 2 + 0];
        float4 q1 = ((const float4*)x)[i * 2 + 1];
        uint4 a;
        a.x = bf16_rne(q0.x) | (bf16_rne(q0.y) << 16);
        a.y = bf16_rne(q0.z) | (bf16_rne(q0.w) << 16);
        a.z = bf16_rne(q1.x) | (bf16_rne(q1.y) << 16);
        a.w = bf16_rne(q1.z) | (bf16_rne(q1.w) << 16);
        xh4[i] = a;
        ob4[i] = make_uint4(0u, 0u, 0u, 0u);   // zero the bf16 aggregation buffer
    }
}

// Streaming edge scatter with packed-bf16 atomics.
// One edge per 32-lane half-wave; lane covers feature pair (2*s2, 2*s2+1).
// ea read sequentially (full HBM BW); xh row = 128B gather (L3); one
// global_atomic_pk_add_bf16 per lane (4B) -> 128B coalesced atomic per edge.
__global__ __launch_bounds__(256) void gine_edges_pk(const unsigned short* __restrict__ xh,
                                                     const int* __restrict__ ei,
                                                     const float* __restrict__ ea,
                                                     unsigned short* __restrict__ outb) {
    int t = blockIdx.x * 256 + threadIdx.x;
    int w = t >> 5;                // edge index (uniform per half-wave)
    int s2 = t & 31;               // feature-pair index
    if (w < N_EDGES) {
        int src = ei[w];               // broadcast load (same addr across half-wave)
        int dst = ei[N_EDGES + w];
        f2v ev = __builtin_nontemporal_load((const f2v*)(ea + (long long)w * D) + s2);
        unsigned int xv = *((const unsigned int*)(xh + (long long)src * D) + s2);
        float mx = fmaxf(ev.x + bf16_lo(xv), 0.0f);
        float my = fmaxf(ev.y + bf16_hi(xv), 0.0f);
        unsigned int pk = bf16_rne(mx) | (bf16_rne(my) << 16);
        void* addr = (void*)(outb + (long long)dst * D + 2 * s2);
        asm volatile("global_atomic_pk_add_bf16 %0, %1, off" :: "v"(addr), "v"(pk) : "memory");
    }
    asm volatile("s_waitcnt vmcnt(0)" ::: "memory");   // drain atomic before endpgm
}

// lin: out = relu((ob_bf16 + (1+eps)*x) @ W^T + b). Base term exact fp32.
__global__ __launch_bounds__(256) void gine_lin(const unsigned short* __restrict__ outb,
                                                const float* __restrict__ x,
                                                const float* __restrict__ W,
                                                const float* __restrict__ bias,
                                                const float* __restrict__ eps,
                                                float* __restrict__ out) {
    __shared__ float Wl[D][D + 1];             // Wl[dd][o] = W[o][dd]
    __shared__ __align__(16) float hl[4][4][D];
    int tid = threadIdx.x;
    for (int i = tid; i < D * D; i += 256) {
        int o = i >> 6, dd = i & 63;
        Wl[dd][o] = W[i];
    }
    __syncthreads();

    int o = tid & 63;
    int wid = __builtin_amdgcn_readfirstlane(threadIdx.x >> 6);
    float bv = bias[o];
    float s = 1.0f + eps[0];
    int base = blockIdx.x * 64 + wid * 16;

    for (int t = 0; t < 4; ++t) {
        int r0 = base + t * 4;
        #pragma unroll
        for (int r = 0; r < 4; ++r) {
            int rr = r0 + r;
            float hv = 0.0f;
            if (rr < N_NODES)
                hv = bf16_f(outb[(long long)rr * D + o]) + s * x[(long long)rr * D + o];
            hl[wid][r][o] = hv;                // wave-private: no barrier needed
        }
        float a0 = bv, a1 = bv, a2 = bv, a3 = bv;
        #pragma unroll
        for (int dq = 0; dq < 16; ++dq) {
            float4 h0 = *(const float4*)&hl[wid][0][dq * 4];
            float4 h1 = *(const float4*)&hl[wid][1][dq * 4];
            float4 h2 = *(const float4*)&hl[wid][2][dq * 4];
            float4 h3 = *(const float4*)&hl[wid][3][dq * 4];
            float w0 = Wl[dq * 4 + 0][o];
            float w1 = Wl[dq * 4 + 1][o];
            float w2 = Wl[dq * 4 + 2][o];
            float w3 = Wl[dq * 4 + 3][o];
            a0 = fmaf(h0.w, w3, fmaf(h0.z, w2, fmaf(h0.y, w1, fmaf(h0.x, w0, a0))));
            a1 = fmaf(h1.w, w3, fmaf(h1.z, w2, fmaf(h1.y, w1, fmaf(h1.x, w0, a1))));
            a2 = fmaf(h2.w, w3, fmaf(h2.z, w2, fmaf(h2.y, w1, fmaf(h2.x, w0, a2))));
            a3 = fmaf(h3.w, w3, fmaf(h3.z, w2, fmaf(h3.y, w1, fmaf(h3.x, w0, a3))));
        }
        if (r0 + 0 < N_NODES) out[(long long)(r0 + 0) * D + o] = fmaxf(a0, 0.0f);
        if (r0 + 1 < N_NODES) out[(long long)(r0 + 1) * D + o] = fmaxf(a1, 0.0f);
        if (r0 + 2 < N_NODES) out[(long long)(r0 + 2) * D + o] = fmaxf(a2, 0.0f);
        if (r0 + 3 < N_NODES) out[(long long)(r0 + 3) * D + o] = fmaxf(a3, 0.0f);
    }
}

// ============ fallback path (fp32 atomic scatter, round-2 proven) ============

__global__ __launch_bounds__(256) void gine_init(const float* __restrict__ x,
                                                 const float* __restrict__ eps,
                                                 float* __restrict__ out, int n4) {
    int i = blockIdx.x * blockDim.x + threadIdx.x;
    float s = 1.0f + eps[0];
    if (i < n4) {
        float4 v = ((const float4*)x)[i];
        v.x *= s; v.y *= s; v.z *= s; v.w *= s;
        ((float4*)out)[i] = v;
    }
}

__global__ __launch_bounds__(256) void gine_edges(const float* __restrict__ x,
                                                  const int* __restrict__ ei,
                                                  const float* __restrict__ ea,
                                                  float* __restrict__ out) {
    int e = blockIdx.x * (blockDim.x >> 6) + (threadIdx.x >> 6);
    int d = threadIdx.x & 63;
    if (e < N_EDGES) {
        int s = ei[e];
        int t = ei[N_EDGES + e];
        float m = x[(long long)s * D + d] + ea[(long long)e * D + d];
        m = fmaxf(m, 0.0f);
        atomicAdd(&out[(long long)t * D + d], m);
    }
}

__global__ __launch_bounds__(256) void gine_linear(float* __restrict__ h,
                                                   const float* __restrict__ W,
                                                   const float* __restrict__ b) {
    __shared__ float Wl[D][D + 1];
    __shared__ float bl[D];
    int tid = threadIdx.x;
    for (int i = tid; i < D * D; i += 256) Wl[i >> 6][i & 63] = W[i];
    if (tid < D) bl[tid] = b[tid];
    __syncthreads();
    int o = tid & 63;
    int row = blockIdx.x * 4 + (tid >> 6);
    if (row < N_NODES) {
        const float* hr = h + (long long)row * D;
        float acc = bl[o];
        #pragma unroll
        for (int d = 0; d < D; ++d) acc = fmaf(hr[d], Wl[o][d], acc);
        h[(long long)row * D + o] = fmaxf(acc, 0.0f);
    }
}

extern "C" void kernel_launch(void* const* d_in, const int* in_sizes, int n_in,
                              void* d_out, int out_size, void* d_ws, size_t ws_size,
                              hipStream_t stream) {
    const float* x   = (const float*)d_in[0];
    const int*   ei  = (const int*)d_in[1];   // int32 on device (harness narrows int64)
    const float* ea  = (const float*)d_in[2];
    const float* W   = (const float*)d_in[3];
    const float* b   = (const float*)d_in[4];
    const float* eps = (const float*)d_in[5];
    float* out = (float*)d_out;

    // ws layout: xh[N*D] bf16 | outb[N*D] bf16
    size_t need = (size_t)N_NODES * D * 2 * 2;
    if (ws_size >= need) {
        unsigned short* xh   = (unsigned short*)d_ws;
        unsigned short* outb = xh + (size_t)N_NODES * D;

        gine_prep<<<(N_NODES * D / 8 + 255) / 256, 256, 0, stream>>>(
            x, (uint4*)xh, (uint4*)outb);
        gine_edges_pk<<<(N_EDGES * 32) / 256, 256, 0, stream>>>(xh, ei, ea, outb);
        gine_lin<<<(N_NODES + 63) / 64, 256, 0, stream>>>(outb, x, W, b, eps, out);
    } else {
        int n4 = (N_NODES * D) / 4;
        gine_init<<<(n4 + 255) / 256, 256, 0, stream>>>(x, eps, out, n4);
        gine_edges<<<(N_EDGES + 3) / 4, 256, 0, stream>>>(x, ei, ea, out);
        gine_linear<<<(N_NODES + 3) / 4, 256, 0, stream>>>(out, W, b);
    }
}

// Round 10
// 220.729 us; speedup vs baseline: 1.3733x; 1.0026x over previous
//
#include <hip/hip_runtime.h>

#define N_NODES 100000
#define N_EDGES 1000000
#define D 64

typedef float f2v __attribute__((ext_vector_type(2)));

__device__ __forceinline__ unsigned int bf16_rne(float f) {
    unsigned int b = __float_as_uint(f);
    return (b + 0x7FFFu + ((b >> 16) & 1u)) >> 16;
}
__device__ __forceinline__ float bf16_lo(unsigned int v) { return __uint_as_float(v << 16); }
__device__ __forceinline__ float bf16_hi(unsigned int v) { return __uint_as_float(v & 0xFFFF0000u); }
__device__ __forceinline__ float bf16_f(unsigned short u) {
    return __uint_as_float(((unsigned int)u) << 16);
}

// prep: xh = bf16(x); ob = bf16((1+eps)*x)  (GIN base folded into the agg buffer).
__global__ __launch_bounds__(256) void gine_prep(const float* __restrict__ x,
                                                 const float* __restrict__ eps,
                                                 uint4* __restrict__ xh4,
                                                 uint4* __restrict__ ob4) {
    int i = blockIdx.x * 256 + threadIdx.x;
    float s = 1.0f + eps[0];
    if (i < N_NODES * D / 8) {
        float4 q0 = ((const float4*)x)[i * 2 + 0];
        float4 q1 = ((const float4*)x)[i * 2 + 1];
        uint4 a;
        a.x = bf16_rne(q0.x) | (bf16_rne(q0.y) << 16);
        a.y = bf16_rne(q0.z) | (bf16_rne(q0.w) << 16);
        a.z = bf16_rne(q1.x) | (bf16_rne(q1.y) << 16);
        a.w = bf16_rne(q1.z) | (bf16_rne(q1.w) << 16);
        xh4[i] = a;
        uint4 o;
        o.x = bf16_rne(s * q0.x) | (bf16_rne(s * q0.y) << 16);
        o.y = bf16_rne(s * q0.z) | (bf16_rne(s * q0.w) << 16);
        o.z = bf16_rne(s * q1.x) | (bf16_rne(s * q1.y) << 16);
        o.w = bf16_rne(s * q1.z) | (bf16_rne(s * q1.w) << 16);
        ob4[i] = o;
    }
}

// Streaming edge scatter with packed-bf16 atomics.
// One edge per 32-lane half-wave; lane covers feature pair (2*s2, 2*s2+1).
__global__ __launch_bounds__(256) void gine_edges_pk(const unsigned short* __restrict__ xh,
                                                     const int* __restrict__ ei,
                                                     const float* __restrict__ ea,
                                                     unsigned short* __restrict__ outb) {
    int t = blockIdx.x * 256 + threadIdx.x;
    int w = t >> 5;                // edge index (uniform per half-wave)
    int s2 = t & 31;               // feature-pair index
    if (w < N_EDGES) {
        int src = ei[w];               // broadcast load (same addr across half-wave)
        int dst = ei[N_EDGES + w];
        f2v ev = __builtin_nontemporal_load((const f2v*)(ea + (long long)w * D) + s2);
        unsigned int xv = *((const unsigned int*)(xh + (long long)src * D) + s2);
        float mx = fmaxf(ev.x + bf16_lo(xv), 0.0f);
        float my = fmaxf(ev.y + bf16_hi(xv), 0.0f);
        unsigned int pk = bf16_rne(mx) | (bf16_rne(my) << 16);
        void* addr = (void*)(outb + (long long)dst * D + 2 * s2);
        asm volatile("global_atomic_pk_add_bf16 %0, %1, off" :: "v"(addr), "v"(pk) : "memory");
    }
    asm volatile("s_waitcnt vmcnt(0)" ::: "memory");   // drain atomic before endpgm
}

// lin: out = relu(ob @ W^T + b); ob already holds (1+eps)x + aggregate.
__global__ __launch_bounds__(256) void gine_lin(const unsigned short* __restrict__ outb,
                                                const float* __restrict__ W,
                                                const float* __restrict__ bias,
                                                float* __restrict__ out) {
    __shared__ float Wl[D][D + 1];             // Wl[dd][o] = W[o][dd]
    __shared__ __align__(16) float hl[4][4][D];
    int tid = threadIdx.x;
    for (int i = tid; i < D * D; i += 256) {
        int o = i >> 6, dd = i & 63;
        Wl[dd][o] = W[i];
    }
    __syncthreads();

    int o = tid & 63;
    int wid = __builtin_amdgcn_readfirstlane(threadIdx.x >> 6);
    float bv = bias[o];
    int base = blockIdx.x * 64 + wid * 16;

    for (int t = 0; t < 4; ++t) {
        int r0 = base + t * 4;
        #pragma unroll
        for (int r = 0; r < 4; ++r) {
            int rr = r0 + r;
            float hv = 0.0f;
            if (rr < N_NODES) hv = bf16_f(outb[(long long)rr * D + o]);
            hl[wid][r][o] = hv;                // wave-private: no barrier needed
        }
        float a0 = bv, a1 = bv, a2 = bv, a3 = bv;
        #pragma unroll
        for (int dq = 0; dq < 16; ++dq) {
            float4 h0 = *(const float4*)&hl[wid][0][dq * 4];
            float4 h1 = *(const float4*)&hl[wid][1][dq * 4];
            float4 h2 = *(const float4*)&hl[wid][2][dq * 4];
            float4 h3 = *(const float4*)&hl[wid][3][dq * 4];
            float w0 = Wl[dq * 4 + 0][o];
            float w1 = Wl[dq * 4 + 1][o];
            float w2 = Wl[dq * 4 + 2][o];
            float w3 = Wl[dq * 4 + 3][o];
            a0 = fmaf(h0.w, w3, fmaf(h0.z, w2, fmaf(h0.y, w1, fmaf(h0.x, w0, a0))));
            a1 = fmaf(h1.w, w3, fmaf(h1.z, w2, fmaf(h1.y, w1, fmaf(h1.x, w0, a1))));
            a2 = fmaf(h2.w, w3, fmaf(h2.z, w2, fmaf(h2.y, w1, fmaf(h2.x, w0, a2))));
            a3 = fmaf(h3.w, w3, fmaf(h3.z, w2, fmaf(h3.y, w1, fmaf(h3.x, w0, a3))));
        }
        if (r0 + 0 < N_NODES) out[(long long)(r0 + 0) * D + o] = fmaxf(a0, 0.0f);
        if (r0 + 1 < N_NODES) out[(long long)(r0 + 1) * D + o] = fmaxf(a1, 0.0f);
        if (r0 + 2 < N_NODES) out[(long long)(r0 + 2) * D + o] = fmaxf(a2, 0.0f);
        if (r0 + 3 < N_NODES) out[(long long)(r0 + 3) * D + o] = fmaxf(a3, 0.0f);
    }
}

// ============ fallback path (fp32 atomic scatter, round-2 proven) ============

__global__ __launch_bounds__(256) void gine_init(const float* __restrict__ x,
                                                 const float* __restrict__ eps,
                                                 float* __restrict__ out, int n4) {
    int i = blockIdx.x * blockDim.x + threadIdx.x;
    float s = 1.0f + eps[0];
    if (i < n4) {
        float4 v = ((const float4*)x)[i];
        v.x *= s; v.y *= s; v.z *= s; v.w *= s;
        ((float4*)out)[i] = v;
    }
}

__global__ __launch_bounds__(256) void gine_edges(const float* __restrict__ x,
                                                  const int* __restrict__ ei,
                                                  const float* __restrict__ ea,
                                                  float* __restrict__ out) {
    int e = blockIdx.x * (blockDim.x >> 6) + (threadIdx.x >> 6);
    int d = threadIdx.x & 63;
    if (e < N_EDGES) {
        int s = ei[e];
        int t = ei[N_EDGES + e];
        float m = x[(long long)s * D + d] + ea[(long long)e * D + d];
        m = fmaxf(m, 0.0f);
        atomicAdd(&out[(long long)t * D + d], m);
    }
}

__global__ __launch_bounds__(256) void gine_linear(float* __restrict__ h,
                                                   const float* __restrict__ W,
                                                   const float* __restrict__ b) {
    __shared__ float Wl[D][D + 1];
    __shared__ float bl[D];
    int tid = threadIdx.x;
    for (int i = tid; i < D * D; i += 256) Wl[i >> 6][i & 63] = W[i];
    if (tid < D) bl[tid] = b[tid];
    __syncthreads();
    int o = tid & 63;
    int row = blockIdx.x * 4 + (tid >> 6);
    if (row < N_NODES) {
        const float* hr = h + (long long)row * D;
        float acc = bl[o];
        #pragma unroll
        for (int d = 0; d < D; ++d) acc = fmaf(hr[d], Wl[o][d], acc);
        h[(long long)row * D + o] = fmaxf(acc, 0.0f);
    }
}

extern "C" void kernel_launch(void* const* d_in, const int* in_sizes, int n_in,
                              void* d_out, int out_size, void* d_ws, size_t ws_size,
                              hipStream_t stream) {
    const float* x   = (const float*)d_in[0];
    const int*   ei  = (const int*)d_in[1];   // int32 on device (harness narrows int64)
    const float* ea  = (const float*)d_in[2];
    const float* W   = (const float*)d_in[3];
    const float* b   = (const float*)d_in[4];
    const float* eps = (const float*)d_in[5];
    float* out = (float*)d_out;

    // ws layout: xh[N*D] bf16 | outb[N*D] bf16
    size_t need = (size_t)N_NODES * D * 2 * 2;
    if (ws_size >= need) {
        unsigned short* xh   = (unsigned short*)d_ws;
        unsigned short* outb = xh + (size_t)N_NODES * D;

        gine_prep<<<(N_NODES * D / 8 + 255) / 256, 256, 0, stream>>>(
            x, eps, (uint4*)xh, (uint4*)outb);
        gine_edges_pk<<<(N_EDGES * 32) / 256, 256, 0, stream>>>(xh, ei, ea, outb);
        gine_lin<<<(N_NODES + 63) / 64, 256, 0, stream>>>(outb, W, b, out);
    } else {
        int n4 = (N_NODES * D) / 4;
        gine_init<<<(n4 + 255) / 256, 256, 0, stream>>>(x, eps, out, n4);
        gine_edges<<<(N_EDGES + 3) / 4, 256, 0, stream>>>(x, ei, ea, out);
        gine_linear<<<(N_NODES + 3) / 4, 256, 0, stream>>>(out, W, b);
    }
}